// Round 4
// baseline (3853.682 us; speedup 1.0000x reference)
//
#include <hip/hip_runtime.h>

#define D 256
#define BROWS 64          // rows per bucket
#define MAXKEY 6272       // >= ceil(n/64)*4 ; supports n <= 100352 (problem: n=100000)
#define PCH 131072        // edges per partition chunk (long runs -> L2 write combining)

typedef __attribute__((ext_vector_type(8))) short short8;
typedef __attribute__((ext_vector_type(4))) float f32x4;

__device__ __forceinline__ ushort f2b(float f) {
    unsigned u = __float_as_uint(f);
    u += 0x7fffu + ((u >> 16) & 1u);   // round-to-nearest-even
    return (ushort)(u >> 16);
}
__device__ __forceinline__ float b2f(ushort h) {
    return __uint_as_float(((unsigned)h) << 16);
}

__global__ void zero_int_kernel(int* __restrict__ p, int n) {
    int stride = gridDim.x * blockDim.x;
    for (int i = blockIdx.x * blockDim.x + threadIdx.x; i < n; i += stride) p[i] = 0;
}

// ---------------- conversions ----------------
__global__ void xconv_kernel(const float* __restrict__ X, ushort* __restrict__ Xb, int total8) {
    int i = blockIdx.x * 256 + threadIdx.x;
    if (i >= total8) return;
    const float4 a = *(const float4*)(X + (size_t)i * 8);
    const float4 b = *(const float4*)(X + (size_t)i * 8 + 4);
    ushort o8[8] = {f2b(a.x), f2b(a.y), f2b(a.z), f2b(a.w),
                    f2b(b.x), f2b(b.y), f2b(b.z), f2b(b.w)};
    *(short8*)(Xb + (size_t)i * 8) = *(const short8*)o8;
}

// WT[h][c][k] = bf16(W[h][k][c])
__global__ void wconv_kernel(const float* __restrict__ W, ushort* __restrict__ WT, int total) {
    int idx = blockIdx.x * 256 + threadIdx.x;
    if (idx >= total) return;
    int h = idx >> 16;
    int c = (idx >> 8) & 255, k = idx & 255;
    WT[(h << 16) + c * 256 + k] = f2b(W[(h << 16) + k * 256 + c]);
}

// ---------------- bucket hist: key = (row>>6)*4 + (row&3), per hop ----------------
__global__ __launch_bounds__(256) void bhist_kernel(const int* __restrict__ rows,
                                                    int* __restrict__ bhistG, int e, int nkey) {
    __shared__ int lh[MAXKEY];
    int h = blockIdx.y;
    const int* r = rows + (size_t)h * e;
    for (int k = threadIdx.x; k < nkey; k += 256) lh[k] = 0;
    __syncthreads();
    int stride = gridDim.x * 256;
    for (int i = blockIdx.x * 256 + threadIdx.x; i < e; i += stride) {
        int row = r[i];
        atomicAdd(&lh[((row >> 6) << 2) | (row & 3)], 1);
    }
    __syncthreads();
    int* g = bhistG + (size_t)h * nkey;
    for (int k = threadIdx.x; k < nkey; k += 256)
        if (lh[k]) atomicAdd(&g[k], lh[k]);
}

// ---------------- scan of all hop*nkey counts -> gbase (+sentinel), gcur ----------------
__global__ __launch_bounds__(1024) void bscan_kernel(const int* __restrict__ bhistG,
                                                     int* __restrict__ gbase,
                                                     int* __restrict__ gcur, int total) {
    __shared__ int s[1024];
    int t = threadIdx.x;
    int C = (total + 1023) >> 10;
    int i0 = t * C, i1 = min(i0 + C, total);
    int sum = 0;
    for (int i = i0; i < i1; ++i) sum += bhistG[i];
    s[t] = sum;
    __syncthreads();
    for (int off = 1; off < 1024; off <<= 1) {
        int x = (t >= off) ? s[t - off] : 0;
        __syncthreads();
        s[t] += x;
        __syncthreads();
    }
    int run = s[t] - sum;   // exclusive
    for (int i = i0; i < i1; ++i) {
        gbase[i] = run; gcur[i] = run;
        run += bhistG[i];
    }
    if (t == 1023) gbase[total] = s[1023];
}

// ---------------- chunked partition: edge payload {col | (row&63)<<24, val} ----------------
__global__ __launch_bounds__(256) void bpart_kernel(const int* __restrict__ rows,
                                                    const int* __restrict__ cols,
                                                    const float* __restrict__ vals,
                                                    int* __restrict__ gcur, int2* __restrict__ eg,
                                                    int e, int nkey) {
    __shared__ int lbase[MAXKEY];
    __shared__ int lcur[MAXKEY];
    int h = blockIdx.y;
    const int*   rr = rows + (size_t)h * e;
    const int*   cc = cols + (size_t)h * e;
    const float* vv = vals + (size_t)h * e;
    int c0 = blockIdx.x * PCH;
    int c1 = min(c0 + PCH, e);
    for (int k = threadIdx.x; k < nkey; k += 256) { lbase[k] = 0; lcur[k] = 0; }
    __syncthreads();
    for (int i = c0 + threadIdx.x; i < c1; i += 256) {
        int row = rr[i];
        atomicAdd(&lbase[((row >> 6) << 2) | (row & 3)], 1);
    }
    __syncthreads();
    int* gc = gcur + (size_t)h * nkey;
    for (int k = threadIdx.x; k < nkey; k += 256) {
        int c = lbase[k];
        lbase[k] = c ? atomicAdd(&gc[k], c) : 0;
    }
    __syncthreads();
    for (int i = c0 + threadIdx.x; i < c1; i += 256) {
        int row = rr[i];
        int k = ((row >> 6) << 2) | (row & 3);
        int p = lbase[k] + atomicAdd(&lcur[k], 1);
        eg[p] = make_int2(cc[i] | ((row & 63) << 24), __float_as_int(vv[i]));
    }
}

// ---------------- bucketed SpMM: Y_h[bucket rows] = A_h X, atomic-free LDS accumulate ----------------
// wave w owns sub-list w (rows == w mod 4) -> disjoint acc rows, non-atomic b128 RMW.
__global__ __launch_bounds__(256) void bspmm_kernel(const int* __restrict__ gbase,
                                                    const int2* __restrict__ eg,
                                                    const ushort* __restrict__ Xb,
                                                    ushort* __restrict__ Y, int n,
                                                    int nkey, int hbase, size_t ystride) {
    __shared__ float acc[BROWS * 256];
    int b = blockIdx.x;
    int h = hbase + blockIdx.y;
    int tid = threadIdx.x;
    for (int i = tid * 4; i < BROWS * 256; i += 1024)
        *(f32x4*)&acc[i] = (f32x4){0.f, 0.f, 0.f, 0.f};
    __syncthreads();

    int w = tid >> 6, lane = tid & 63;
    int key = h * nkey + (b << 2) + w;
    int s = gbase[key], t = gbase[key + 1];
    int l4 = lane * 4;

    int2 pe[4]; ushort4 pg[4];
    #pragma unroll
    for (int d = 0; d < 4; ++d) {
        int idx = s + d;
        pe[d] = (idx < t) ? eg[idx] : make_int2(0, 0);
        pg[d] = (idx < t) ? *(const ushort4*)(Xb + (size_t)(pe[d].x & 0xFFFFFF) * 256 + l4)
                          : make_ushort4(0, 0, 0, 0);
    }
    for (int i = s; i < t; i += 4) {
        #pragma unroll
        for (int d = 0; d < 4; ++d) {
            if (i + d < t) {
                int2 ce = pe[d]; ushort4 cg = pg[d];
                int nx = i + 4 + d;
                pe[d] = (nx < t) ? eg[nx] : make_int2(0, 0);
                pg[d] = (nx < t) ? *(const ushort4*)(Xb + (size_t)(pe[d].x & 0xFFFFFF) * 256 + l4)
                                 : make_ushort4(0, 0, 0, 0);
                float val = __int_as_float(ce.y);
                int j = ((unsigned)ce.x) >> 24;
                float* ap = &acc[j * 256 + l4];
                f32x4 a = *(f32x4*)ap;
                a.x = fmaf(val, b2f(cg.x), a.x);
                a.y = fmaf(val, b2f(cg.y), a.y);
                a.z = fmaf(val, b2f(cg.z), a.z);
                a.w = fmaf(val, b2f(cg.w), a.w);
                *(f32x4*)ap = a;
            }
        }
    }
    __syncthreads();
    // write 64 rows x 256 cols as bf16; thread -> (row j = tid/4, 64-col strip)
    ushort* Yh = Y + (size_t)blockIdx.y * ystride;
    int j = tid >> 2;
    int coff = (tid & 3) * 64;
    int grow = b * 64 + j;
    if (grow < n) {
        ushort* dst = Yh + (size_t)grow * 256 + coff;
        const float* src = &acc[j * 256 + coff];
        #pragma unroll
        for (int q = 0; q < 8; ++q) {
            ushort o8[8];
            #pragma unroll
            for (int z = 0; z < 8; ++z) o8[z] = f2b(src[q * 8 + z]);
            *(short8*)(dst + q * 8) = *(const short8*)o8;
        }
    }
}

// ---------------- GEMM: out = [relu](Σ_h Y_h @ W_h) [+ prev out] ----------------
#define APAD 40

__global__ __launch_bounds__(256) void gemmY_kernel(const ushort* __restrict__ Y,
                                                    const ushort* __restrict__ WT,
                                                    float* __restrict__ out, int M,
                                                    int nh, int mode) {
    __shared__ ushort As[64 * APAD];
    __shared__ ushort Bs[64 * APAD];
    int tid = threadIdx.x;
    int r0 = blockIdx.x * 64, c0 = blockIdx.y * 64;
    int w = tid >> 6, lane = tid & 63;
    int wr = w >> 1, wc = w & 1;
    int lo = lane & 15, hi = lane >> 4;
    f32x4 acc[2][2] = {};
    int srow = tid >> 2;
    int skoff = (tid & 3) * 8;
    int arow = r0 + srow; if (arow > M - 1) arow = M - 1;
    for (int h = 0; h < nh; ++h) {
        const ushort* ap = Y + ((size_t)h * M + arow) * 256 + skoff;
        const ushort* bp = WT + ((size_t)h << 16) + (size_t)(c0 + srow) * 256 + skoff;
        for (int kk = 0; kk < 256; kk += 32) {
            short8 av = *(const short8*)(ap + kk);
            short8 bv = *(const short8*)(bp + kk);
            __syncthreads();
            *(short8*)&As[srow * APAD + skoff] = av;
            *(short8*)&Bs[srow * APAD + skoff] = bv;
            __syncthreads();
            short8 a0 = *(const short8*)&As[(wr * 32 +      lo) * APAD + hi * 8];
            short8 a1 = *(const short8*)&As[(wr * 32 + 16 + lo) * APAD + hi * 8];
            short8 b0 = *(const short8*)&Bs[(wc * 32 +      lo) * APAD + hi * 8];
            short8 b1 = *(const short8*)&Bs[(wc * 32 + 16 + lo) * APAD + hi * 8];
            acc[0][0] = __builtin_amdgcn_mfma_f32_16x16x32_bf16(a0, b0, acc[0][0], 0, 0, 0);
            acc[0][1] = __builtin_amdgcn_mfma_f32_16x16x32_bf16(a0, b1, acc[0][1], 0, 0, 0);
            acc[1][0] = __builtin_amdgcn_mfma_f32_16x16x32_bf16(a1, b0, acc[1][0], 0, 0, 0);
            acc[1][1] = __builtin_amdgcn_mfma_f32_16x16x32_bf16(a1, b1, acc[1][1], 0, 0, 0);
        }
    }
    for (int mi = 0; mi < 2; ++mi)
        for (int ni = 0; ni < 2; ++ni)
            for (int i = 0; i < 4; ++i) {
                int row = r0 + wr * 32 + mi * 16 + hi * 4 + i;
                int col = c0 + wc * 32 + ni * 16 + lo;
                if (row < M) {
                    float v = acc[mi][ni][i];
                    float* op = &out[(size_t)row * 256 + col];
                    if (mode & 1) v += *op;
                    if (mode & 2) v = fmaxf(v, 0.f);
                    *op = v;
                }
            }
}

extern "C" void kernel_launch(void* const* d_in, const int* in_sizes, int n_in,
                              void* d_out, int out_size, void* d_ws, size_t ws_size,
                              hipStream_t stream) {
    const float* X    = (const float*)d_in[0];
    const float* W    = (const float*)d_in[1];
    const float* vals = (const float*)d_in[2];
    const int*   rows = (const int*)d_in[3];
    const int*   cols = (const int*)d_in[4];
    int n    = in_sizes[0] / D;         // 100000
    int hops = in_sizes[1] / (D * D);   // 3
    int e    = in_sizes[2] / hops;      // 3200000

    int nbuk    = (n + 63) / 64;        // 1563
    int nkey    = nbuk * 4;             // 6252 (<= MAXKEY)
    int nkeytot = hops * nkey;
    int nchunks = (e + PCH - 1) / PCH;  // 25

    float* out = (float*)d_out;

    auto padded = [](size_t b) { return (b + 255) & ~(size_t)255; };
    size_t sz_WT   = padded((size_t)hops * D * D * 2);
    size_t sz_Xb   = padded((size_t)n * D * 2);
    size_t sz_hist = padded((size_t)nkeytot * 4);
    size_t sz_gb   = padded((size_t)(nkeytot + 1) * 4);
    size_t sz_gc   = padded((size_t)nkeytot * 4);
    size_t sz_eg   = padded((size_t)hops * e * 8);
    size_t sz_Yall = padded((size_t)hops * n * D * 2);
    size_t sz_Y1   = padded((size_t)n * D * 2);
    size_t common  = sz_WT + sz_Xb + sz_hist + sz_gb + sz_gc + sz_eg;
    bool bigY = (ws_size >= common + sz_Yall);

    char* wsb = (char*)d_ws;
    size_t off = 0;
    auto alloc = [&](size_t bytes) -> void* { void* p = wsb + off; off += padded(bytes); return p; };

    ushort* WT     = (ushort*)alloc((size_t)hops * D * D * 2);
    ushort* Xb     = (ushort*)alloc((size_t)n * D * 2);
    int*    bhistG = (int*)   alloc((size_t)nkeytot * 4);
    int*    gbase  = (int*)   alloc((size_t)(nkeytot + 1) * 4);
    int*    gcur   = (int*)   alloc((size_t)nkeytot * 4);
    int2*   edges  = (int2*)  alloc((size_t)hops * e * 8);
    ushort* Y      = (ushort*)alloc(bigY ? (size_t)hops * n * D * 2 : (size_t)n * D * 2);

    // conversions (independent)
    xconv_kernel<<<(n * D / 8 + 255) / 256, 256, 0, stream>>>(X, Xb, n * D / 8);
    wconv_kernel<<<(hops * D * D + 255) / 256, 256, 0, stream>>>(W, WT, hops * D * D);

    // bucket CSR-lite build
    zero_int_kernel<<<(nkeytot + 255) / 256, 256, 0, stream>>>(bhistG, nkeytot);
    bhist_kernel<<<dim3(64, hops), 256, 0, stream>>>(rows, bhistG, e, nkey);
    bscan_kernel<<<1, 1024, 0, stream>>>(bhistG, gbase, gcur, nkeytot);
    bpart_kernel<<<dim3(nchunks, hops), 256, 0, stream>>>(rows, cols, vals, gcur, edges, e, nkey);

    if (bigY) {
        bspmm_kernel<<<dim3(nbuk, hops), 256, 0, stream>>>(gbase, edges, Xb, Y, n, nkey,
                                                           0, (size_t)n * D);
        gemmY_kernel<<<dim3((n + 63) / 64, D / 64), 256, 0, stream>>>(Y, WT, out, n, hops, 2);
    } else {
        for (int h = 0; h < hops; ++h) {
            bspmm_kernel<<<dim3(nbuk, 1), 256, 0, stream>>>(gbase, edges, Xb, Y, n, nkey, h, 0);
            int mode = (h > 0 ? 1 : 0) | (h == hops - 1 ? 2 : 0);
            gemmY_kernel<<<dim3((n + 63) / 64, D / 64), 256, 0, stream>>>(Y, WT + (size_t)h * D * D,
                                                                          out, n, 1, mode);
        }
    }
}

// Round 5
// 1291.121 us; speedup vs baseline: 2.9848x; 2.9848x over previous
//
#include <hip/hip_runtime.h>

#define D 256
#define MAXKEY 1600       // >= ceil(n/64); supports n <= 102400 (problem: n=100000)
#define PCH 32768         // edges per partition chunk (294 blocks -> saturates 256 CUs)

typedef __attribute__((ext_vector_type(8))) short short8;
typedef __attribute__((ext_vector_type(4))) float f32x4;

__device__ __forceinline__ ushort f2b(float f) {
    unsigned u = __float_as_uint(f);
    u += 0x7fffu + ((u >> 16) & 1u);   // round-to-nearest-even
    return (ushort)(u >> 16);
}
__device__ __forceinline__ float b2f(ushort h) {
    return __uint_as_float(((unsigned)h) << 16);
}
__device__ __forceinline__ long long ntload_ll(const void* p) {
    return __builtin_nontemporal_load((const long long*)p);
}

__global__ void zero_int_kernel(int* __restrict__ p, int n) {
    int stride = gridDim.x * blockDim.x;
    for (int i = blockIdx.x * blockDim.x + threadIdx.x; i < n; i += stride) p[i] = 0;
}

// ---------------- conversions ----------------
__global__ void xconv_kernel(const float* __restrict__ X, ushort* __restrict__ Xb, int total8) {
    int i = blockIdx.x * 256 + threadIdx.x;
    if (i >= total8) return;
    const float4 a = *(const float4*)(X + (size_t)i * 8);
    const float4 b = *(const float4*)(X + (size_t)i * 8 + 4);
    ushort o8[8] = {f2b(a.x), f2b(a.y), f2b(a.z), f2b(a.w),
                    f2b(b.x), f2b(b.y), f2b(b.z), f2b(b.w)};
    *(short8*)(Xb + (size_t)i * 8) = *(const short8*)o8;
}

// WT[h][c][k] = bf16(W[h][k][c])
__global__ void wconv_kernel(const float* __restrict__ W, ushort* __restrict__ WT, int total) {
    int idx = blockIdx.x * 256 + threadIdx.x;
    if (idx >= total) return;
    int h = idx >> 16;
    int c = (idx >> 8) & 255, k = idx & 255;
    WT[(h << 16) + c * 256 + k] = f2b(W[(h << 16) + k * 256 + c]);
}

// ---------------- bucket hist: key = row>>6, per hop ----------------
__global__ __launch_bounds__(256) void bhist_kernel(const int* __restrict__ rows,
                                                    int* __restrict__ bhistG, int e, int nbuk) {
    __shared__ int lh[MAXKEY];
    int h = blockIdx.y;
    const int* r = rows + (size_t)h * e;
    for (int k = threadIdx.x; k < nbuk; k += 256) lh[k] = 0;
    __syncthreads();
    int stride = gridDim.x * 256;
    for (int i = blockIdx.x * 256 + threadIdx.x; i < e; i += stride)
        atomicAdd(&lh[r[i] >> 6], 1);
    __syncthreads();
    int* g = bhistG + (size_t)h * nbuk;
    for (int k = threadIdx.x; k < nbuk; k += 256)
        if (lh[k]) atomicAdd(&g[k], lh[k]);
}

// ---------------- scan of hop*nbuk counts -> gbase (+sentinel), gcur ----------------
__global__ __launch_bounds__(1024) void bscan_kernel(const int* __restrict__ bhistG,
                                                     int* __restrict__ gbase,
                                                     int* __restrict__ gcur, int total) {
    __shared__ int s[1024];
    int t = threadIdx.x;
    int C = (total + 1023) >> 10;
    int i0 = t * C, i1 = min(i0 + C, total);
    int sum = 0;
    for (int i = i0; i < i1; ++i) sum += bhistG[i];
    s[t] = sum;
    __syncthreads();
    for (int off = 1; off < 1024; off <<= 1) {
        int x = (t >= off) ? s[t - off] : 0;
        __syncthreads();
        s[t] += x;
        __syncthreads();
    }
    int run = s[t] - sum;   // exclusive
    for (int i = i0; i < i1; ++i) {
        gbase[i] = run; gcur[i] = run;
        run += bhistG[i];
    }
    if (t == 1023) gbase[total] = s[1023];
}

// ---------------- chunked partition: payload {col | (row&63)<<24, val} ----------------
__global__ __launch_bounds__(256) void bpart_kernel(const int* __restrict__ rows,
                                                    const int* __restrict__ cols,
                                                    const float* __restrict__ vals,
                                                    int* __restrict__ gcur, int2* __restrict__ raw,
                                                    int e, int nbuk) {
    __shared__ int lbase[MAXKEY];
    __shared__ int lcur[MAXKEY];
    int h = blockIdx.y;
    const int*   rr = rows + (size_t)h * e;
    const int*   cc = cols + (size_t)h * e;
    const float* vv = vals + (size_t)h * e;
    int c0 = blockIdx.x * PCH;
    int c1 = min(c0 + PCH, e);
    if (c0 >= c1) return;
    for (int k = threadIdx.x; k < nbuk; k += 256) { lbase[k] = 0; lcur[k] = 0; }
    __syncthreads();
    for (int i = c0 + threadIdx.x; i < c1; i += 256)
        atomicAdd(&lbase[rr[i] >> 6], 1);
    __syncthreads();
    int* gc = gcur + (size_t)h * nbuk;
    for (int k = threadIdx.x; k < nbuk; k += 256) {
        int c = lbase[k];
        lbase[k] = c ? atomicAdd(&gc[k], c) : 0;
    }
    __syncthreads();
    for (int i = c0 + threadIdx.x; i < c1; i += 256) {
        int row = rr[i];
        int p = lbase[row >> 6] + atomicAdd(&lcur[row >> 6], 1);
        raw[p] = make_int2(cc[i] | ((row & 63) << 24), __float_as_int(vv[i]));
    }
}

// ---------------- per-bucket exact sort -> edges2 + exact row_ptr (absolute) ----------------
__global__ __launch_bounds__(256) void bsort_kernel(const int* __restrict__ gbase,
                                                    const int2* __restrict__ raw,
                                                    int2* __restrict__ eg,
                                                    int* __restrict__ row_ptr,
                                                    int n, int nbuk) {
    __shared__ int hist[64], excl[64], cur[64];
    int key = blockIdx.x;            // 0 .. hops*nbuk-1
    int h = key / nbuk, b = key % nbuk;
    int s = gbase[key], t = gbase[key + 1];
    int tid = threadIdx.x;
    if (tid < 64) hist[tid] = 0;
    __syncthreads();
    for (int i = s + tid; i < t; i += 256)
        atomicAdd(&hist[(((unsigned)raw[i].x) >> 24) & 63], 1);
    __syncthreads();
    if (tid == 0) {
        int run = s;
        for (int j = 0; j < 64; ++j) { excl[j] = run; cur[j] = run; run += hist[j]; }
    }
    __syncthreads();
    int* rp = row_ptr + (size_t)h * (n + 1);
    if (tid < 64) {
        int grow = b * 64 + tid;
        if (grow < n) rp[grow] = excl[tid];
    }
    if (tid == 0 && b == nbuk - 1) rp[n] = t;
    for (int i = s + tid; i < t; i += 256) {
        int2 ev = raw[i];
        int j = (((unsigned)ev.x) >> 24) & 63;
        int p = atomicAdd(&cur[j], 1);
        eg[p] = ev;   // row bits kept; spmm masks them off
    }
}

// ---------------- SpMM: one wave per row, register accumulate, 4-deep pipeline ----------------
// rp holds ABSOLUTE indices into eg. Edge loads nontemporal; Y stores nontemporal
// (protects the 51MB Xb gather target in L3).
__global__ __launch_bounds__(256) void spmmX_kernel(const int* __restrict__ rp,
                                                    const int2* __restrict__ eg,
                                                    const ushort* __restrict__ Xb,
                                                    ushort* __restrict__ Yh, int n) {
    int w = threadIdx.x >> 6, lane = threadIdx.x & 63;
    int r = blockIdx.x * 4 + w;
    if (r >= n) return;
    int half = lane >> 5, l5 = lane & 31;
    int doff = l5 * 8;
    int e0 = rp[r], e1 = rp[r + 1];
    float acc[8] = {};
    int m0 = e0 + half, m1 = e0 + 2 + half;
    long long ev0 = (m0 < e1) ? ntload_ll(eg + m0) : 0;
    long long ev1 = (m1 < e1) ? ntload_ll(eg + m1) : 0;
    for (int ee = e0; ee < e1; ee += 4) {
        long long c0 = ev0, c1 = ev1;
        int n0 = ee + 4 + half, n1 = ee + 6 + half;
        ev0 = (n0 < e1) ? ntload_ll(eg + n0) : 0;
        ev1 = (n1 < e1) ? ntload_ll(eg + n1) : 0;
        int col0 = ((int)(unsigned)c0) & 0xFFFFFF;
        int col1 = ((int)(unsigned)c1) & 0xFFFFFF;
        short8 v0 = *(const short8*)(Xb + (size_t)col0 * 256 + doff);
        short8 v1 = *(const short8*)(Xb + (size_t)col1 * 256 + doff);
        float val0 = __int_as_float((int)(c0 >> 32));
        float val1 = __int_as_float((int)(c1 >> 32));
        #pragma unroll
        for (int i = 0; i < 8; ++i)
            acc[i] = fmaf(val0, b2f((ushort)v0[i]), acc[i]);
        #pragma unroll
        for (int i = 0; i < 8; ++i)
            acc[i] = fmaf(val1, b2f((ushort)v1[i]), acc[i]);
    }
    #pragma unroll
    for (int i = 0; i < 8; ++i)
        acc[i] += __shfl_xor(acc[i], 32);
    if (half == 0) {
        union { ushort u[8]; long long ll[2]; } o;
        #pragma unroll
        for (int i = 0; i < 8; ++i) o.u[i] = f2b(acc[i]);
        long long* dst = (long long*)(Yh + (size_t)r * 256 + doff);
        __builtin_nontemporal_store(o.ll[0], dst);
        __builtin_nontemporal_store(o.ll[1], dst + 1);
    }
}

// ---------------- GEMM: out = [relu](Y @ W_h [+ prev out]) ----------------
#define APAD 40

__global__ __launch_bounds__(256) void gemmY_kernel(const ushort* __restrict__ Y,
                                                    const ushort* __restrict__ WT,
                                                    float* __restrict__ out, int M,
                                                    int nh, int mode) {
    __shared__ ushort As[64 * APAD];
    __shared__ ushort Bs[64 * APAD];
    int tid = threadIdx.x;
    int r0 = blockIdx.x * 64, c0 = blockIdx.y * 64;
    int w = tid >> 6, lane = tid & 63;
    int wr = w >> 1, wc = w & 1;
    int lo = lane & 15, hi = lane >> 4;
    f32x4 acc[2][2] = {};
    int srow = tid >> 2;
    int skoff = (tid & 3) * 8;
    int arow = r0 + srow; if (arow > M - 1) arow = M - 1;
    for (int h = 0; h < nh; ++h) {
        const ushort* ap = Y + ((size_t)h * M + arow) * 256 + skoff;
        const ushort* bp = WT + ((size_t)h << 16) + (size_t)(c0 + srow) * 256 + skoff;
        for (int kk = 0; kk < 256; kk += 32) {
            short8 av = *(const short8*)(ap + kk);
            short8 bv = *(const short8*)(bp + kk);
            __syncthreads();
            *(short8*)&As[srow * APAD + skoff] = av;
            *(short8*)&Bs[srow * APAD + skoff] = bv;
            __syncthreads();
            short8 a0 = *(const short8*)&As[(wr * 32 +      lo) * APAD + hi * 8];
            short8 a1 = *(const short8*)&As[(wr * 32 + 16 + lo) * APAD + hi * 8];
            short8 b0 = *(const short8*)&Bs[(wc * 32 +      lo) * APAD + hi * 8];
            short8 b1 = *(const short8*)&Bs[(wc * 32 + 16 + lo) * APAD + hi * 8];
            acc[0][0] = __builtin_amdgcn_mfma_f32_16x16x32_bf16(a0, b0, acc[0][0], 0, 0, 0);
            acc[0][1] = __builtin_amdgcn_mfma_f32_16x16x32_bf16(a0, b1, acc[0][1], 0, 0, 0);
            acc[1][0] = __builtin_amdgcn_mfma_f32_16x16x32_bf16(a1, b0, acc[1][0], 0, 0, 0);
            acc[1][1] = __builtin_amdgcn_mfma_f32_16x16x32_bf16(a1, b1, acc[1][1], 0, 0, 0);
        }
    }
    for (int mi = 0; mi < 2; ++mi)
        for (int ni = 0; ni < 2; ++ni)
            for (int i = 0; i < 4; ++i) {
                int row = r0 + wr * 32 + mi * 16 + hi * 4 + i;
                int col = c0 + wc * 32 + ni * 16 + lo;
                if (row < M) {
                    float v = acc[mi][ni][i];
                    float* op = &out[(size_t)row * 256 + col];
                    if (mode & 1) v += *op;
                    if (mode & 2) v = fmaxf(v, 0.f);
                    *op = v;
                }
            }
}

extern "C" void kernel_launch(void* const* d_in, const int* in_sizes, int n_in,
                              void* d_out, int out_size, void* d_ws, size_t ws_size,
                              hipStream_t stream) {
    const float* X    = (const float*)d_in[0];
    const float* W    = (const float*)d_in[1];
    const float* vals = (const float*)d_in[2];
    const int*   rows = (const int*)d_in[3];
    const int*   cols = (const int*)d_in[4];
    int n    = in_sizes[0] / D;         // 100000
    int hops = in_sizes[1] / (D * D);   // 3
    int e    = in_sizes[2] / hops;      // 3200000

    int nbuk    = (n + 63) / 64;        // 1563 (<= MAXKEY)
    int nkeytot = hops * nbuk;          // 4689
    int nchunks = (e + PCH - 1) / PCH;  // 98

    float* out = (float*)d_out;

    auto padded = [](size_t b) { return (b + 255) & ~(size_t)255; };
    char* wsb = (char*)d_ws;
    size_t off = 0;
    auto alloc = [&](size_t bytes) -> void* { void* p = wsb + off; off += padded(bytes); return p; };

    ushort* WT      = (ushort*)alloc((size_t)hops * D * D * 2);     //  0.4 MB
    ushort* Xb      = (ushort*)alloc((size_t)n * D * 2);            // 51.2 MB
    int*    bhistG  = (int*)   alloc((size_t)nkeytot * 4);
    int*    gbase   = (int*)   alloc((size_t)(nkeytot + 1) * 4);
    int*    gcur    = (int*)   alloc((size_t)nkeytot * 4);
    int2*   raw     = (int2*)  alloc((size_t)hops * e * 8);         // 76.8 MB (reused as Y)
    int2*   edges   = (int2*)  alloc((size_t)hops * e * 8);         // 76.8 MB
    int*    row_ptr = (int*)   alloc((size_t)hops * (n + 1) * 4);   //  1.2 MB
    ushort* Y       = (ushort*)raw;   // raw is dead after bsort; 51.2MB <= 76.8MB

    // conversions (independent of partition)
    xconv_kernel<<<(n * D / 8 + 255) / 256, 256, 0, stream>>>(X, Xb, n * D / 8);
    wconv_kernel<<<(hops * D * D + 255) / 256, 256, 0, stream>>>(W, WT, hops * D * D);

    // bucket partition + per-bucket exact sort -> exact CSR
    zero_int_kernel<<<(nkeytot + 255) / 256, 256, 0, stream>>>(bhistG, nkeytot);
    bhist_kernel<<<dim3(128, hops), 256, 0, stream>>>(rows, bhistG, e, nbuk);
    bscan_kernel<<<1, 1024, 0, stream>>>(bhistG, gbase, gcur, nkeytot);
    bpart_kernel<<<dim3(nchunks, hops), 256, 0, stream>>>(rows, cols, vals, gcur, raw, e, nbuk);
    bsort_kernel<<<nkeytot, 256, 0, stream>>>(gbase, raw, edges, row_ptr, n, nbuk);

    // per-hop: SpMM (gather from L3-resident Xb) then GEMM accumulate into out
    for (int h = 0; h < hops; ++h) {
        spmmX_kernel<<<(n + 3) / 4, 256, 0, stream>>>(row_ptr + (size_t)h * (n + 1), edges, Xb, Y, n);
        int mode = (h > 0 ? 1 : 0) | (h == hops - 1 ? 2 : 0);
        gemmY_kernel<<<dim3((n + 63) / 64, D / 64), 256, 0, stream>>>(Y, WT + (size_t)h * D * D,
                                                                      out, n, 1, mode);
    }
}

// Round 6
// 1193.293 us; speedup vs baseline: 3.2295x; 1.0820x over previous
//
#include <hip/hip_runtime.h>

#define D 256
#define MAXB 512          // >= ceil(n/256); supports n <= 131072 (problem: n=100000)
#define PCH 32768         // edges per partition chunk (294 blocks -> saturates 256 CUs)

typedef __attribute__((ext_vector_type(8))) short short8;
typedef __attribute__((ext_vector_type(4))) float f32x4;

__device__ __forceinline__ ushort f2b(float f) {
    unsigned u = __float_as_uint(f);
    u += 0x7fffu + ((u >> 16) & 1u);   // round-to-nearest-even
    return (ushort)(u >> 16);
}
__device__ __forceinline__ float b2f(ushort h) {
    return __uint_as_float(((unsigned)h) << 16);
}
__device__ __forceinline__ long long ntload_ll(const void* p) {
    return __builtin_nontemporal_load((const long long*)p);
}

__global__ void zero_int_kernel(int* __restrict__ p, int n) {
    int stride = gridDim.x * blockDim.x;
    for (int i = blockIdx.x * blockDim.x + threadIdx.x; i < n; i += stride) p[i] = 0;
}

// ---------------- conversions ----------------
__global__ void xconv_kernel(const float* __restrict__ X, ushort* __restrict__ Xb, int total8) {
    int i = blockIdx.x * 256 + threadIdx.x;
    if (i >= total8) return;
    const float4 a = *(const float4*)(X + (size_t)i * 8);
    const float4 b = *(const float4*)(X + (size_t)i * 8 + 4);
    ushort o8[8] = {f2b(a.x), f2b(a.y), f2b(a.z), f2b(a.w),
                    f2b(b.x), f2b(b.y), f2b(b.z), f2b(b.w)};
    *(short8*)(Xb + (size_t)i * 8) = *(const short8*)o8;
}

// WT[h][c][k] = bf16(W[h][k][c])
__global__ void wconv_kernel(const float* __restrict__ W, ushort* __restrict__ WT, int total) {
    int idx = blockIdx.x * 256 + threadIdx.x;
    if (idx >= total) return;
    int h = idx >> 16;
    int c = (idx >> 8) & 255, k = idx & 255;
    WT[(h << 16) + c * 256 + k] = f2b(W[(h << 16) + k * 256 + c]);
}

// ---------------- bucket hist: key = row>>8 (256-row buckets), per hop ----------------
__global__ __launch_bounds__(256) void bhist_kernel(const int* __restrict__ rows,
                                                    int* __restrict__ bhistG, int e, int nbuk) {
    __shared__ int lh[MAXB];
    int h = blockIdx.y;
    const int* r = rows + (size_t)h * e;
    for (int k = threadIdx.x; k < nbuk; k += 256) lh[k] = 0;
    __syncthreads();
    int stride = gridDim.x * 256;
    for (int i = blockIdx.x * 256 + threadIdx.x; i < e; i += stride)
        atomicAdd(&lh[r[i] >> 8], 1);
    __syncthreads();
    int* g = bhistG + (size_t)h * nbuk;
    for (int k = threadIdx.x; k < nbuk; k += 256)
        if (lh[k]) atomicAdd(&g[k], lh[k]);
}

// ---------------- scan of hop*nbuk counts -> gbase (+sentinel), gcur ----------------
__global__ __launch_bounds__(1024) void bscan_kernel(const int* __restrict__ bhistG,
                                                     int* __restrict__ gbase,
                                                     int* __restrict__ gcur, int total) {
    __shared__ int s[1024];
    int t = threadIdx.x;
    int C = (total + 1023) >> 10;
    int i0 = t * C, i1 = min(i0 + C, total);
    int sum = 0;
    for (int i = i0; i < i1; ++i) sum += bhistG[i];
    s[t] = sum;
    __syncthreads();
    for (int off = 1; off < 1024; off <<= 1) {
        int x = (t >= off) ? s[t - off] : 0;
        __syncthreads();
        s[t] += x;
        __syncthreads();
    }
    int run = s[t] - sum;   // exclusive
    for (int i = i0; i < i1; ++i) {
        gbase[i] = run; gcur[i] = run;
        run += bhistG[i];
    }
    if (t == 1023) gbase[total] = s[1023];
}

// ---------------- chunked partition: payload {col | (row&255)<<17, val} ----------------
__global__ __launch_bounds__(256) void bpart_kernel(const int* __restrict__ rows,
                                                    const int* __restrict__ cols,
                                                    const float* __restrict__ vals,
                                                    int* __restrict__ gcur, int2* __restrict__ raw,
                                                    int e, int nbuk) {
    __shared__ int lbase[MAXB];
    __shared__ int lcur[MAXB];
    int h = blockIdx.y;
    const int*   rr = rows + (size_t)h * e;
    const int*   cc = cols + (size_t)h * e;
    const float* vv = vals + (size_t)h * e;
    int c0 = blockIdx.x * PCH;
    int c1 = min(c0 + PCH, e);
    if (c0 >= c1) return;
    for (int k = threadIdx.x; k < nbuk; k += 256) { lbase[k] = 0; lcur[k] = 0; }
    __syncthreads();
    for (int i = c0 + threadIdx.x; i < c1; i += 256)
        atomicAdd(&lbase[rr[i] >> 8], 1);
    __syncthreads();
    int* gc = gcur + (size_t)h * nbuk;
    for (int k = threadIdx.x; k < nbuk; k += 256) {
        int c = lbase[k];
        lbase[k] = c ? atomicAdd(&gc[k], c) : 0;
    }
    __syncthreads();
    for (int i = c0 + threadIdx.x; i < c1; i += 256) {
        int row = rr[i];
        int b = row >> 8;
        int p = lbase[b] + atomicAdd(&lcur[b], 1);
        raw[p] = make_int2(cc[i] | ((row & 255) << 17), __float_as_int(vv[i]));
    }
}

// ---------------- per-bucket exact sort -> eg + exact row_ptr (absolute) ----------------
__global__ __launch_bounds__(256) void bsort_kernel(const int* __restrict__ gbase,
                                                    const int2* __restrict__ raw,
                                                    int2* __restrict__ eg,
                                                    int* __restrict__ row_ptr,
                                                    int n, int nbuk) {
    __shared__ int hist[256], ss[256], cur[256];
    int key = blockIdx.x;            // 0 .. hops*nbuk-1
    int h = key / nbuk, b = key % nbuk;
    int s = gbase[key], t = gbase[key + 1];
    int tid = threadIdx.x;
    hist[tid] = 0;
    __syncthreads();
    for (int i = s + tid; i < t; i += 256)
        atomicAdd(&hist[(((unsigned)raw[i].x) >> 17) & 255], 1);
    __syncthreads();
    int v = hist[tid];
    ss[tid] = v;
    __syncthreads();
    for (int off = 1; off < 256; off <<= 1) {
        int x = (tid >= off) ? ss[tid - off] : 0;
        __syncthreads();
        ss[tid] += x;
        __syncthreads();
    }
    int excl = s + ss[tid] - v;      // absolute row start
    cur[tid] = excl;
    int* rp = row_ptr + (size_t)h * (n + 1);
    int grow = b * 256 + tid;        // 1:1 thread -> row
    if (grow < n) rp[grow] = excl;
    if (tid == 255 && b == nbuk - 1) rp[n] = t;
    __syncthreads();
    for (int i = s + tid; i < t; i += 256) {
        int2 ev = raw[i];
        int j = (((unsigned)ev.x) >> 17) & 255;
        int p = atomicAdd(&cur[j], 1);
        eg[p] = ev;   // row bits kept; spmm masks them off
    }
}

// ---------------- SpMM: one wave per row, register accumulate, 4-deep pipeline ----------------
__global__ __launch_bounds__(256) void spmmX_kernel(const int* __restrict__ rp,
                                                    const int2* __restrict__ eg,
                                                    const ushort* __restrict__ Xb,
                                                    ushort* __restrict__ Yh, int n) {
    int w = threadIdx.x >> 6, lane = threadIdx.x & 63;
    int r = blockIdx.x * 4 + w;
    if (r >= n) return;
    int half = lane >> 5, l5 = lane & 31;
    int doff = l5 * 8;
    int e0 = rp[r], e1 = rp[r + 1];
    float acc[8] = {};
    int m0 = e0 + half, m1 = e0 + 2 + half;
    long long ev0 = (m0 < e1) ? ntload_ll(eg + m0) : 0;
    long long ev1 = (m1 < e1) ? ntload_ll(eg + m1) : 0;
    for (int ee = e0; ee < e1; ee += 4) {
        long long c0 = ev0, c1 = ev1;
        int n0 = ee + 4 + half, n1 = ee + 6 + half;
        ev0 = (n0 < e1) ? ntload_ll(eg + n0) : 0;
        ev1 = (n1 < e1) ? ntload_ll(eg + n1) : 0;
        int col0 = ((int)(unsigned)c0) & 0x1FFFF;
        int col1 = ((int)(unsigned)c1) & 0x1FFFF;
        short8 v0 = *(const short8*)(Xb + (size_t)col0 * 256 + doff);
        short8 v1 = *(const short8*)(Xb + (size_t)col1 * 256 + doff);
        float val0 = __int_as_float((int)(c0 >> 32));
        float val1 = __int_as_float((int)(c1 >> 32));
        #pragma unroll
        for (int i = 0; i < 8; ++i)
            acc[i] = fmaf(val0, b2f((ushort)v0[i]), acc[i]);
        #pragma unroll
        for (int i = 0; i < 8; ++i)
            acc[i] = fmaf(val1, b2f((ushort)v1[i]), acc[i]);
    }
    #pragma unroll
    for (int i = 0; i < 8; ++i)
        acc[i] += __shfl_xor(acc[i], 32);
    if (half == 0) {
        union { ushort u[8]; long long ll[2]; } o;
        #pragma unroll
        for (int i = 0; i < 8; ++i) o.u[i] = f2b(acc[i]);
        long long* dst = (long long*)(Yh + (size_t)r * 256 + doff);
        __builtin_nontemporal_store(o.ll[0], dst);
        __builtin_nontemporal_store(o.ll[1], dst + 1);
    }
}

// ---------------- GEMM: out = [relu](Σ_h Y_h @ W_h) [+ prev out] ----------------
#define APAD 40

__global__ __launch_bounds__(256) void gemmY_kernel(const ushort* __restrict__ Y,
                                                    const ushort* __restrict__ WT,
                                                    float* __restrict__ out, int M,
                                                    int nh, int mode) {
    __shared__ ushort As[64 * APAD];
    __shared__ ushort Bs[64 * APAD];
    int tid = threadIdx.x;
    int r0 = blockIdx.x * 64, c0 = blockIdx.y * 64;
    int w = tid >> 6, lane = tid & 63;
    int wr = w >> 1, wc = w & 1;
    int lo = lane & 15, hi = lane >> 4;
    f32x4 acc[2][2] = {};
    int srow = tid >> 2;
    int skoff = (tid & 3) * 8;
    int arow = r0 + srow; if (arow > M - 1) arow = M - 1;
    for (int h = 0; h < nh; ++h) {
        const ushort* ap = Y + ((size_t)h * M + arow) * 256 + skoff;
        const ushort* bp = WT + ((size_t)h << 16) + (size_t)(c0 + srow) * 256 + skoff;
        for (int kk = 0; kk < 256; kk += 32) {
            short8 av = *(const short8*)(ap + kk);
            short8 bv = *(const short8*)(bp + kk);
            __syncthreads();
            *(short8*)&As[srow * APAD + skoff] = av;
            *(short8*)&Bs[srow * APAD + skoff] = bv;
            __syncthreads();
            short8 a0 = *(const short8*)&As[(wr * 32 +      lo) * APAD + hi * 8];
            short8 a1 = *(const short8*)&As[(wr * 32 + 16 + lo) * APAD + hi * 8];
            short8 b0 = *(const short8*)&Bs[(wc * 32 +      lo) * APAD + hi * 8];
            short8 b1 = *(const short8*)&Bs[(wc * 32 + 16 + lo) * APAD + hi * 8];
            acc[0][0] = __builtin_amdgcn_mfma_f32_16x16x32_bf16(a0, b0, acc[0][0], 0, 0, 0);
            acc[0][1] = __builtin_amdgcn_mfma_f32_16x16x32_bf16(a0, b1, acc[0][1], 0, 0, 0);
            acc[1][0] = __builtin_amdgcn_mfma_f32_16x16x32_bf16(a1, b0, acc[1][0], 0, 0, 0);
            acc[1][1] = __builtin_amdgcn_mfma_f32_16x16x32_bf16(a1, b1, acc[1][1], 0, 0, 0);
        }
    }
    for (int mi = 0; mi < 2; ++mi)
        for (int ni = 0; ni < 2; ++ni)
            for (int i = 0; i < 4; ++i) {
                int row = r0 + wr * 32 + mi * 16 + hi * 4 + i;
                int col = c0 + wc * 32 + ni * 16 + lo;
                if (row < M) {
                    float v = acc[mi][ni][i];
                    float* op = &out[(size_t)row * 256 + col];
                    if (mode & 1) v += *op;
                    if (mode & 2) v = fmaxf(v, 0.f);
                    *op = v;
                }
            }
}

extern "C" void kernel_launch(void* const* d_in, const int* in_sizes, int n_in,
                              void* d_out, int out_size, void* d_ws, size_t ws_size,
                              hipStream_t stream) {
    const float* X    = (const float*)d_in[0];
    const float* W    = (const float*)d_in[1];
    const float* vals = (const float*)d_in[2];
    const int*   rows = (const int*)d_in[3];
    const int*   cols = (const int*)d_in[4];
    int n    = in_sizes[0] / D;         // 100000
    int hops = in_sizes[1] / (D * D);   // 3
    int e    = in_sizes[2] / hops;      // 3200000

    int nbuk    = (n + 255) / 256;      // 391 (<= MAXB)
    int nkeytot = hops * nbuk;          // 1173
    int nchunks = (e + PCH - 1) / PCH;  // 98

    float* out = (float*)d_out;

    auto padded = [](size_t b) { return (b + 255) & ~(size_t)255; };
    char* wsb = (char*)d_ws;
    size_t off = 0;
    auto alloc = [&](size_t bytes) -> void* { void* p = wsb + off; off += padded(bytes); return p; };

    // raw is LAST so Y (=3*n*D*2 bytes) can overlay it and extend into the ws tail
    ushort* WT      = (ushort*)alloc((size_t)hops * D * D * 2);     //  0.4 MB
    ushort* Xb      = (ushort*)alloc((size_t)n * D * 2);            // 51.2 MB
    int*    bhistG  = (int*)   alloc((size_t)nkeytot * 4);
    int*    gbase   = (int*)   alloc((size_t)(nkeytot + 1) * 4);
    int*    gcur    = (int*)   alloc((size_t)nkeytot * 4);
    int*    row_ptr = (int*)   alloc((size_t)hops * (n + 1) * 4);   //  1.2 MB
    int2*   edges   = (int2*)  alloc((size_t)hops * e * 8);         // 76.8 MB
    size_t  raw_off = off;
    int2*   raw     = (int2*)  alloc((size_t)hops * e * 8);         // 76.8 MB (dead after bsort)

    bool bigY = (ws_size >= raw_off + (size_t)hops * n * D * 2);
    ushort* Y = (ushort*)raw;   // fused: [hops][n][D] over raw+tail; else per-hop [n][D]

    // conversions (independent of partition)
    xconv_kernel<<<(n * D / 8 + 255) / 256, 256, 0, stream>>>(X, Xb, n * D / 8);
    wconv_kernel<<<(hops * D * D + 255) / 256, 256, 0, stream>>>(W, WT, hops * D * D);

    // bucket partition + per-bucket exact sort -> exact CSR
    zero_int_kernel<<<(nkeytot + 255) / 256, 256, 0, stream>>>(bhistG, nkeytot);
    bhist_kernel<<<dim3(128, hops), 256, 0, stream>>>(rows, bhistG, e, nbuk);
    bscan_kernel<<<1, 1024, 0, stream>>>(bhistG, gbase, gcur, nkeytot);
    bpart_kernel<<<dim3(nchunks, hops), 256, 0, stream>>>(rows, cols, vals, gcur, raw, e, nbuk);
    bsort_kernel<<<nkeytot, 256, 0, stream>>>(gbase, raw, edges, row_ptr, n, nbuk);

    if (bigY) {
        for (int h = 0; h < hops; ++h)
            spmmX_kernel<<<(n + 3) / 4, 256, 0, stream>>>(row_ptr + (size_t)h * (n + 1), edges,
                                                          Xb, Y + (size_t)h * n * D, n);
        gemmY_kernel<<<dim3((n + 63) / 64, D / 64), 256, 0, stream>>>(Y, WT, out, n, hops, 2);
    } else {
        for (int h = 0; h < hops; ++h) {
            spmmX_kernel<<<(n + 3) / 4, 256, 0, stream>>>(row_ptr + (size_t)h * (n + 1), edges,
                                                          Xb, Y, n);
            int mode = (h > 0 ? 1 : 0) | (h == hops - 1 ? 2 : 0);
            gemmY_kernel<<<dim3((n + 63) / 64, D / 64), 256, 0, stream>>>(Y, WT + (size_t)h * D * D,
                                                                          out, n, 1, mode);
        }
    }
}

// Round 7
// 1135.841 us; speedup vs baseline: 3.3928x; 1.0506x over previous
//
#include <hip/hip_runtime.h>

#define D 256
#define MAXB 128          // >= ceil(n/1024); supports n <= 131072 (problem: n=100000)
#define PCH 16384         // edges per partition chunk (588 blocks -> real TLP)

typedef __attribute__((ext_vector_type(8))) short short8;
typedef __attribute__((ext_vector_type(4))) float f32x4;

__device__ __forceinline__ ushort f2b(float f) {
    unsigned u = __float_as_uint(f);
    u += 0x7fffu + ((u >> 16) & 1u);   // round-to-nearest-even
    return (ushort)(u >> 16);
}
__device__ __forceinline__ float b2f(ushort h) {
    return __uint_as_float(((unsigned)h) << 16);
}
__device__ __forceinline__ long long ntload_ll(const void* p) {
    return __builtin_nontemporal_load((const long long*)p);
}

__global__ void zero_int_kernel(int* __restrict__ p, int n) {
    int stride = gridDim.x * blockDim.x;
    for (int i = blockIdx.x * blockDim.x + threadIdx.x; i < n; i += stride) p[i] = 0;
}

// ---------------- conversions ----------------
__global__ void xconv_kernel(const float* __restrict__ X, ushort* __restrict__ Xb, int total8) {
    int i = blockIdx.x * 256 + threadIdx.x;
    if (i >= total8) return;
    const float4 a = *(const float4*)(X + (size_t)i * 8);
    const float4 b = *(const float4*)(X + (size_t)i * 8 + 4);
    ushort o8[8] = {f2b(a.x), f2b(a.y), f2b(a.z), f2b(a.w),
                    f2b(b.x), f2b(b.y), f2b(b.z), f2b(b.w)};
    *(short8*)(Xb + (size_t)i * 8) = *(const short8*)o8;
}

// WT[h][c][k] = bf16(W[h][k][c])
__global__ void wconv_kernel(const float* __restrict__ W, ushort* __restrict__ WT, int total) {
    int idx = blockIdx.x * 256 + threadIdx.x;
    if (idx >= total) return;
    int h = idx >> 16;
    int c = (idx >> 8) & 255, k = idx & 255;
    WT[(h << 16) + c * 256 + k] = f2b(W[(h << 16) + k * 256 + c]);
}

// ---------------- bucket hist: key = row>>10 (1024-row buckets), per hop ----------------
__global__ __launch_bounds__(256) void bhist_kernel(const int* __restrict__ rows,
                                                    int* __restrict__ bhistG, int e, int nbuk) {
    __shared__ int lh[MAXB];
    int h = blockIdx.y;
    const int* r = rows + (size_t)h * e;
    for (int k = threadIdx.x; k < nbuk; k += 256) lh[k] = 0;
    __syncthreads();
    int stride = gridDim.x * 256;
    for (int i = blockIdx.x * 256 + threadIdx.x; i < e; i += stride)
        atomicAdd(&lh[r[i] >> 10], 1);
    __syncthreads();
    int* g = bhistG + (size_t)h * nbuk;
    for (int k = threadIdx.x; k < nbuk; k += 256)
        if (lh[k]) atomicAdd(&g[k], lh[k]);
}

// ---------------- scan of hop*nbuk counts -> gbase (+sentinel), gcur ----------------
__global__ __launch_bounds__(1024) void bscan_kernel(const int* __restrict__ bhistG,
                                                     int* __restrict__ gbase,
                                                     int* __restrict__ gcur, int total) {
    __shared__ int s[1024];
    int t = threadIdx.x;
    int C = (total + 1023) >> 10;
    int i0 = t * C, i1 = min(i0 + C, total);
    int sum = 0;
    for (int i = i0; i < i1; ++i) sum += bhistG[i];
    s[t] = sum;
    __syncthreads();
    for (int off = 1; off < 1024; off <<= 1) {
        int x = (t >= off) ? s[t - off] : 0;
        __syncthreads();
        s[t] += x;
        __syncthreads();
    }
    int run = s[t] - sum;   // exclusive
    for (int i = i0; i < i1; ++i) {
        gbase[i] = run; gcur[i] = run;
        run += bhistG[i];
    }
    if (t == 1023) gbase[total] = s[1023];
}

// ---------------- chunked partition: payload {col | (row&1023)<<17, val} ----------------
__global__ __launch_bounds__(512) void bpart_kernel(const int* __restrict__ rows,
                                                    const int* __restrict__ cols,
                                                    const float* __restrict__ vals,
                                                    int* __restrict__ gcur, int2* __restrict__ raw,
                                                    int e, int nbuk) {
    __shared__ int lbase[MAXB];
    __shared__ int lcur[MAXB];
    int h = blockIdx.y;
    const int*   rr = rows + (size_t)h * e;
    const int*   cc = cols + (size_t)h * e;
    const float* vv = vals + (size_t)h * e;
    int c0 = blockIdx.x * PCH;
    int c1 = min(c0 + PCH, e);
    if (c0 >= c1) return;
    for (int k = threadIdx.x; k < nbuk; k += 512) { lbase[k] = 0; lcur[k] = 0; }
    __syncthreads();
    for (int i = c0 + threadIdx.x; i < c1; i += 512)
        atomicAdd(&lbase[rr[i] >> 10], 1);
    __syncthreads();
    int* gc = gcur + (size_t)h * nbuk;
    for (int k = threadIdx.x; k < nbuk; k += 512) {
        int c = lbase[k];
        lbase[k] = c ? atomicAdd(&gc[k], c) : 0;
    }
    __syncthreads();
    for (int i = c0 + threadIdx.x; i < c1; i += 512) {
        int row = rr[i];
        int b = row >> 10;
        int p = lbase[b] + atomicAdd(&lcur[b], 1);
        raw[p] = make_int2(cc[i] | ((row & 1023) << 17), __float_as_int(vv[i]));
    }
}

// ---------------- per-bucket exact sort -> eg + exact row_ptr (absolute) ----------------
// bucket = 1024 rows (~33K edges, 262KB region: L2-resident scatter)
__global__ __launch_bounds__(512) void bsort_kernel(const int* __restrict__ gbase,
                                                    const int2* __restrict__ raw,
                                                    int2* __restrict__ eg,
                                                    int* __restrict__ row_ptr,
                                                    int n, int nbuk) {
    __shared__ int hist[1024];
    __shared__ int ss[512];
    __shared__ int cur[1024];
    int key = blockIdx.x;            // 0 .. hops*nbuk-1
    int h = key / nbuk, b = key % nbuk;
    int s = gbase[key], t = gbase[key + 1];
    int tid = threadIdx.x;
    hist[tid] = 0; hist[tid + 512] = 0;
    __syncthreads();
    for (int i = s + tid; i < t; i += 512)
        atomicAdd(&hist[(((unsigned)raw[i].x) >> 17) & 1023], 1);
    __syncthreads();
    int a = hist[2 * tid], c = hist[2 * tid + 1];
    int pair = a + c;
    ss[tid] = pair;
    __syncthreads();
    for (int off = 1; off < 512; off <<= 1) {
        int x = (tid >= off) ? ss[tid - off] : 0;
        __syncthreads();
        ss[tid] += x;
        __syncthreads();
    }
    int excl = s + ss[tid] - pair;   // absolute start of row 2*tid in this bucket
    cur[2 * tid] = excl;
    cur[2 * tid + 1] = excl + a;
    int* rp = row_ptr + (size_t)h * (n + 1);
    int grow = b * 1024 + 2 * tid;
    if (grow < n)     rp[grow]     = excl;
    if (grow + 1 < n) rp[grow + 1] = excl + a;
    if (tid == 511 && b == nbuk - 1) rp[n] = t;
    __syncthreads();
    for (int i = s + tid; i < t; i += 512) {
        int2 ev = raw[i];
        int j = (((unsigned)ev.x) >> 17) & 1023;
        int p = atomicAdd(&cur[j], 1);
        eg[p] = ev;   // row bits kept; spmm masks them off
    }
}

// ---------------- SpMM: one wave per row, quarter-wave per edge, pipelined gathers ----------------
// 4 edges per step, gathers issued one full step ahead (~8-12 VMEM in flight/wave).
__global__ __launch_bounds__(256) void spmmX_kernel(const int* __restrict__ rp,
                                                    const int2* __restrict__ eg,
                                                    const ushort* __restrict__ Xb,
                                                    ushort* __restrict__ Yh, int n) {
    int w = threadIdx.x >> 6, lane = threadIdx.x & 63;
    int r = blockIdx.x * 4 + w;
    if (r >= n) return;
    int g = lane >> 4, l4 = lane & 15;
    int doff = l4 * 16;               // 16 cols (32B) per lane
    const ushort* xb = Xb + doff;
    int e0 = rp[r], e1 = rp[r + 1];
    float acc[16] = {};

    int i0 = e0 + g;
    long long d_cur = (i0 < e1) ? ntload_ll(eg + i0) : 0;
    int c_cur = ((int)(unsigned)d_cur) & 0x1FFFF;
    short8 va = *(const short8*)(xb + (size_t)c_cur * 256);
    short8 vb = *(const short8*)(xb + (size_t)c_cur * 256 + 8);
    int i1 = e0 + 4 + g;
    long long d_nxt = (i1 < e1) ? ntload_ll(eg + i1) : 0;

    for (int ee = e0; ee < e1; ee += 4) {
        // issue next step's gathers + desc prefetch before consuming current
        int c_nxt = ((int)(unsigned)d_nxt) & 0x1FFFF;
        short8 wa = *(const short8*)(xb + (size_t)c_nxt * 256);
        short8 wb = *(const short8*)(xb + (size_t)c_nxt * 256 + 8);
        int i2 = ee + 8 + g;
        long long d_n2 = (i2 < e1) ? ntload_ll(eg + i2) : 0;

        float val = __int_as_float((int)(d_cur >> 32));
        #pragma unroll
        for (int i = 0; i < 8; ++i)
            acc[i] = fmaf(val, b2f((ushort)va[i]), acc[i]);
        #pragma unroll
        for (int i = 0; i < 8; ++i)
            acc[8 + i] = fmaf(val, b2f((ushort)vb[i]), acc[8 + i]);

        d_cur = d_nxt; va = wa; vb = wb; d_nxt = d_n2;
    }
    // combine 4 quarter-wave partials
    #pragma unroll
    for (int i = 0; i < 16; ++i) acc[i] += __shfl_xor(acc[i], 16);
    #pragma unroll
    for (int i = 0; i < 16; ++i) acc[i] += __shfl_xor(acc[i], 32);
    if (g == 0) {
        union { ushort u[16]; long long ll[4]; } o;
        #pragma unroll
        for (int i = 0; i < 16; ++i) o.u[i] = f2b(acc[i]);
        long long* dst = (long long*)(Yh + (size_t)r * 256 + doff);
        __builtin_nontemporal_store(o.ll[0], dst);
        __builtin_nontemporal_store(o.ll[1], dst + 1);
        __builtin_nontemporal_store(o.ll[2], dst + 2);
        __builtin_nontemporal_store(o.ll[3], dst + 3);
    }
}

// ---------------- GEMM: out = [relu](Σ_h Y_h @ W_h) [+ prev out] ----------------
#define APAD 40

__global__ __launch_bounds__(256) void gemmY_kernel(const ushort* __restrict__ Y,
                                                    const ushort* __restrict__ WT,
                                                    float* __restrict__ out, int M,
                                                    int nh, int mode) {
    __shared__ ushort As[64 * APAD];
    __shared__ ushort Bs[64 * APAD];
    int tid = threadIdx.x;
    int r0 = blockIdx.x * 64, c0 = blockIdx.y * 64;
    int w = tid >> 6, lane = tid & 63;
    int wr = w >> 1, wc = w & 1;
    int lo = lane & 15, hi = lane >> 4;
    f32x4 acc[2][2] = {};
    int srow = tid >> 2;
    int skoff = (tid & 3) * 8;
    int arow = r0 + srow; if (arow > M - 1) arow = M - 1;
    for (int h = 0; h < nh; ++h) {
        const ushort* ap = Y + ((size_t)h * M + arow) * 256 + skoff;
        const ushort* bp = WT + ((size_t)h << 16) + (size_t)(c0 + srow) * 256 + skoff;
        for (int kk = 0; kk < 256; kk += 32) {
            short8 av = *(const short8*)(ap + kk);
            short8 bv = *(const short8*)(bp + kk);
            __syncthreads();
            *(short8*)&As[srow * APAD + skoff] = av;
            *(short8*)&Bs[srow * APAD + skoff] = bv;
            __syncthreads();
            short8 a0 = *(const short8*)&As[(wr * 32 +      lo) * APAD + hi * 8];
            short8 a1 = *(const short8*)&As[(wr * 32 + 16 + lo) * APAD + hi * 8];
            short8 b0 = *(const short8*)&Bs[(wc * 32 +      lo) * APAD + hi * 8];
            short8 b1 = *(const short8*)&Bs[(wc * 32 + 16 + lo) * APAD + hi * 8];
            acc[0][0] = __builtin_amdgcn_mfma_f32_16x16x32_bf16(a0, b0, acc[0][0], 0, 0, 0);
            acc[0][1] = __builtin_amdgcn_mfma_f32_16x16x32_bf16(a0, b1, acc[0][1], 0, 0, 0);
            acc[1][0] = __builtin_amdgcn_mfma_f32_16x16x32_bf16(a1, b0, acc[1][0], 0, 0, 0);
            acc[1][1] = __builtin_amdgcn_mfma_f32_16x16x32_bf16(a1, b1, acc[1][1], 0, 0, 0);
        }
    }
    for (int mi = 0; mi < 2; ++mi)
        for (int ni = 0; ni < 2; ++ni)
            for (int i = 0; i < 4; ++i) {
                int row = r0 + wr * 32 + mi * 16 + hi * 4 + i;
                int col = c0 + wc * 32 + ni * 16 + lo;
                if (row < M) {
                    float v = acc[mi][ni][i];
                    float* op = &out[(size_t)row * 256 + col];
                    if (mode & 1) v += *op;
                    if (mode & 2) v = fmaxf(v, 0.f);
                    *op = v;
                }
            }
}

extern "C" void kernel_launch(void* const* d_in, const int* in_sizes, int n_in,
                              void* d_out, int out_size, void* d_ws, size_t ws_size,
                              hipStream_t stream) {
    const float* X    = (const float*)d_in[0];
    const float* W    = (const float*)d_in[1];
    const float* vals = (const float*)d_in[2];
    const int*   rows = (const int*)d_in[3];
    const int*   cols = (const int*)d_in[4];
    int n    = in_sizes[0] / D;         // 100000
    int hops = in_sizes[1] / (D * D);   // 3
    int e    = in_sizes[2] / hops;      // 3200000

    int nbuk    = (n + 1023) / 1024;    // 98 (<= MAXB)
    int nkeytot = hops * nbuk;          // 294
    int nchunks = (e + PCH - 1) / PCH;  // 196

    float* out = (float*)d_out;

    auto padded = [](size_t b) { return (b + 255) & ~(size_t)255; };
    char* wsb = (char*)d_ws;
    size_t off = 0;
    auto alloc = [&](size_t bytes) -> void* { void* p = wsb + off; off += padded(bytes); return p; };

    // raw is LAST so Y (=hops*n*D*2 bytes) can overlay it and extend into the ws tail
    ushort* WT      = (ushort*)alloc((size_t)hops * D * D * 2);     //  0.4 MB
    ushort* Xb      = (ushort*)alloc((size_t)n * D * 2);            // 51.2 MB
    int*    bhistG  = (int*)   alloc((size_t)nkeytot * 4);
    int*    gbase   = (int*)   alloc((size_t)(nkeytot + 1) * 4);
    int*    gcur    = (int*)   alloc((size_t)nkeytot * 4);
    int*    row_ptr = (int*)   alloc((size_t)hops * (n + 1) * 4);   //  1.2 MB
    int2*   edges   = (int2*)  alloc((size_t)hops * e * 8);         // 76.8 MB
    size_t  raw_off = off;
    int2*   raw     = (int2*)  alloc((size_t)hops * e * 8);         // 76.8 MB (dead after bsort)

    bool bigY = (ws_size >= raw_off + (size_t)hops * n * D * 2);
    ushort* Y = (ushort*)raw;   // fused: [hops][n][D] over raw+tail; else per-hop [n][D]

    // conversions (independent of partition)
    xconv_kernel<<<(n * D / 8 + 255) / 256, 256, 0, stream>>>(X, Xb, n * D / 8);
    wconv_kernel<<<(hops * D * D + 255) / 256, 256, 0, stream>>>(W, WT, hops * D * D);

    // coarse bucket partition + per-bucket exact sort -> exact CSR
    zero_int_kernel<<<(nkeytot + 255) / 256, 256, 0, stream>>>(bhistG, nkeytot);
    bhist_kernel<<<dim3(128, hops), 256, 0, stream>>>(rows, bhistG, e, nbuk);
    bscan_kernel<<<1, 1024, 0, stream>>>(bhistG, gbase, gcur, nkeytot);
    bpart_kernel<<<dim3(nchunks, hops), 512, 0, stream>>>(rows, cols, vals, gcur, raw, e, nbuk);
    bsort_kernel<<<nkeytot, 512, 0, stream>>>(gbase, raw, edges, row_ptr, n, nbuk);

    if (bigY) {
        for (int h = 0; h < hops; ++h)
            spmmX_kernel<<<(n + 3) / 4, 256, 0, stream>>>(row_ptr + (size_t)h * (n + 1), edges,
                                                          Xb, Y + (size_t)h * n * D, n);
        gemmY_kernel<<<dim3((n + 63) / 64, D / 64), 256, 0, stream>>>(Y, WT, out, n, hops, 2);
    } else {
        for (int h = 0; h < hops; ++h) {
            spmmX_kernel<<<(n + 3) / 4, 256, 0, stream>>>(row_ptr + (size_t)h * (n + 1), edges,
                                                          Xb, Y, n);
            int mode = (h > 0 ? 1 : 0) | (h == hops - 1 ? 2 : 0);
            gemmY_kernel<<<dim3((n + 63) / 64, D / 64), 256, 0, stream>>>(Y, WT + (size_t)h * D * D,
                                                                          out, n, 1, mode);
        }
    }
}